// Round 8
// baseline (1947.978 us; speedup 1.0000x reference)
//
#include <hip/hip_runtime.h>
#include <hip/hip_bf16.h>
#include <cstdint>
#include <cstddef>

// Problem constants: N=32768, D=2048, H=4096, E=8, T = N/E = 4096.
#define NTOK 32768
#define DDIM 2048
#define HDIM 4096
#define NEXP 8
#define TTOK 4096

typedef __attribute__((ext_vector_type(8))) __bf16 bf16x8;
typedef __attribute__((ext_vector_type(4))) float f32x4;

#define MFMA_BF16(a, b, c) __builtin_amdgcn_mfma_f32_16x16x32_bf16((a), (b), (c), 0, 0, 0)
#define SBAR() __builtin_amdgcn_s_barrier()
#define SCHED0() __builtin_amdgcn_sched_barrier(0)
#define WAIT_VM(n) asm volatile("s_waitcnt vmcnt(" #n ")" ::: "memory")
#define WAIT_LGKM0() asm volatile("s_waitcnt lgkmcnt(0)" ::: "memory")

__device__ __forceinline__ unsigned short f2bf(float f) {
  unsigned int u = __builtin_bit_cast(unsigned int, f);
  u += 0x7FFFu + ((u >> 16) & 1u);   // round-to-nearest-even
  return (unsigned short)(u >> 16);
}

// ---------------- f32 -> bf16 convert (vectorized, grid-stride) ----------------
__global__ __launch_bounds__(256) void cvt_kernel(const float* __restrict__ src,
                                                  unsigned short* __restrict__ dst,
                                                  long n4) {
  long i = (long)blockIdx.x * blockDim.x + threadIdx.x;
  long stride = (long)gridDim.x * blockDim.x;
  const float4* s4 = (const float4*)src;
  ushort4* d4 = (ushort4*)dst;
  for (; i < n4; i += stride) {
    float4 v = s4[i];
    ushort4 o;
    o.x = f2bf(v.x); o.y = f2bf(v.y); o.z = f2bf(v.z); o.w = f2bf(v.w);
    d4[i] = o;
  }
}

// ------------- transpose w_down (E,H,D) f32 -> (E,D,H) bf16 -------------
__global__ __launch_bounds__(256) void transpose_wd(const float* __restrict__ w,
                                                    unsigned short* __restrict__ wt) {
  __shared__ unsigned short tile[64][66];
  const int e = blockIdx.z;
  const int h0 = blockIdx.y * 64;
  const int d0 = blockIdx.x * 64;
  const float* we = w + (size_t)e * HDIM * DDIM;
  unsigned short* wte = wt + (size_t)e * DDIM * HDIM;
  const int t = threadIdx.x;
  const int r = t >> 4;
  const int c4 = (t & 15) * 4;
#pragma unroll
  for (int p = 0; p < 4; ++p) {
    int h = r + p * 16;
    float4 v = *(const float4*)(we + (size_t)(h0 + h) * DDIM + d0 + c4);
    tile[h][c4 + 0] = f2bf(v.x);
    tile[h][c4 + 1] = f2bf(v.y);
    tile[h][c4 + 2] = f2bf(v.z);
    tile[h][c4 + 3] = f2bf(v.w);
  }
  __syncthreads();
#pragma unroll
  for (int p = 0; p < 4; ++p) {
    int d = r + p * 16;
    ushort4 o;
    o.x = tile[c4 + 0][d];
    o.y = tile[c4 + 1][d];
    o.z = tile[c4 + 2][d];
    o.w = tile[c4 + 3][d];
    *(ushort4*)(wte + (size_t)(d0 + d) * HDIM + h0 + c4) = o;
  }
}

// ------------- GEMM staging: 128 rows x 64 bf16, global_load_lds width=16 -------------
// LDS dest linear; swizzle via inverse-XOR on the GLOBAL source granule (rule #21).
// 4 global_load_lds per thread per call (256 threads). Proven 0 bank conflicts.
__device__ __forceinline__ void stage128x64(const unsigned short* __restrict__ g0,
                                            size_t stride_elems,
                                            unsigned short* lds, int tid) {
#pragma unroll
  for (int i = 0; i < 4; ++i) {
    int gi = i * 256 + tid;          // granule index 0..1023 (16B granules)
    int r = gi >> 3;                 // row 0..127
    int c = gi & 7;                  // granule-in-row 0..7
    const unsigned short* src = g0 + (size_t)r * stride_elems + ((c ^ (r & 7)) << 3);
    __builtin_amdgcn_global_load_lds(
        (const __attribute__((address_space(1))) unsigned int*)src,
        (__attribute__((address_space(3))) unsigned int*)(lds + (size_t)gi * 8),
        16, 0, 0);
  }
}

__device__ __forceinline__ bf16x8 read_frag(const unsigned short* lds, int row, int cg) {
  return *(const bf16x8*)(lds + row * 64 + ((cg ^ (row & 7)) << 3));
}

// ------------- GEMM1 + SwiGLU: 128x128 tile, split-stage minimal-sync pipeline -------------
// A (x) single-buffered 16KB; Bu/Bg double-buffered 2x16KB each = 80KB total -> 2 blocks/CU.
// Iter t: vmcnt(8)+SBAR -> compute(sA, sBu/g[t&1]) -> LGKM0+SBAR -> stage A(t+1), B(t+2).
// 2 barriers/K-tile; B ~2 iterations in flight; cross-block TLP hides sync drift.
__global__ __launch_bounds__(256, 2) void gemm1_swiglu(
    const unsigned short* __restrict__ Xb,
    const unsigned short* __restrict__ Wb,
    unsigned short* __restrict__ Hid) {
  __shared__ unsigned short sA[128 * 64];        // 16 KiB
  __shared__ unsigned short sBu[2][128 * 64];    // 32 KiB
  __shared__ unsigned short sBg[2][128 * 64];    // 32 KiB
  const int bn = blockIdx.x;   // h tile 0..31
  const int bm = blockIdx.y;   // token tile 0..31
  const int e  = blockIdx.z;
  const unsigned short* Xe = Xb + ((size_t)e * TTOK + bm * 128) * DDIM;
  const unsigned short* Wu = Wb + ((size_t)e * 2 * HDIM + (size_t)bn * 128) * DDIM;
  const unsigned short* Wg = Wu + (size_t)HDIM * DDIM;
  const int tid = threadIdx.x;
  const int lane = tid & 63;
  const int wid = tid >> 6;
  const int wm = (wid & 1) * 64;
  const int wn = (wid >> 1) * 64;
  const int lr = lane & 15;
  const int lk = lane >> 4;

  f32x4 au[4][4], ag[4][4];
#pragma unroll
  for (int i = 0; i < 4; ++i)
#pragma unroll
    for (int j = 0; j < 4; ++j) {
      au[i][j] = f32x4{0.f, 0.f, 0.f, 0.f};
      ag[i][j] = f32x4{0.f, 0.f, 0.f, 0.f};
    }

  const int NT = DDIM / 64;   // 32
  // Prologue issue order matters for vmcnt counting: B(0)(8), A(0)(4), B(1)(8).
  stage128x64(Wu, DDIM, sBu[0], tid);
  stage128x64(Wg, DDIM, sBg[0], tid);
  stage128x64(Xe, DDIM, sA, tid);
  stage128x64(Wu + 64, DDIM, sBu[1], tid);
  stage128x64(Wg + 64, DDIM, sBg[1], tid);

  for (int t = 0; t < NT; ++t) {
    const int cur = t & 1;
    // Wait: B(t)+A(t) landed (the 12 oldest); leave B(t+1)'s 8 in flight.
    if (t + 1 < NT) { WAIT_VM(8); } else { WAIT_VM(0); }
    SBAR();
    SCHED0();
    const unsigned short* bu = sBu[cur];
    const unsigned short* bg = sBg[cur];
#pragma unroll
    for (int kh = 0; kh < 2; ++kh) {
      const int cg = kh * 4 + lk;
      bf16x8 a[4], u[4], g[4];
#pragma unroll
      for (int mi = 0; mi < 4; ++mi) a[mi] = read_frag(sA, wm + mi * 16 + lr, cg);
#pragma unroll
      for (int ni = 0; ni < 4; ++ni) u[ni] = read_frag(bu, wn + ni * 16 + lr, cg);
#pragma unroll
      for (int ni = 0; ni < 4; ++ni) g[ni] = read_frag(bg, wn + ni * 16 + lr, cg);
#pragma unroll
      for (int mi = 0; mi < 4; ++mi)
#pragma unroll
        for (int ni = 0; ni < 4; ++ni) {
          au[mi][ni] = MFMA_BF16(a[mi], u[ni], au[mi][ni]);
          ag[mi][ni] = MFMA_BF16(a[mi], g[ni], ag[mi][ni]);
        }
    }
    SCHED0();
    WAIT_LGKM0();
    SBAR();                 // all waves done reading sA and sB*[cur]
    SCHED0();
    if (t + 1 < NT) stage128x64(Xe + (t + 1) * 64, DDIM, sA, tid);          // A(t+1): 4 loads
    if (t + 2 < NT) {
      stage128x64(Wu + (t + 2) * 64, DDIM, sBu[cur], tid);                  // B(t+2): 8 loads
      stage128x64(Wg + (t + 2) * 64, DDIM, sBg[cur], tid);
    }
  }

  unsigned short* He = Hid + ((size_t)e * TTOK + bm * 128) * HDIM + (size_t)bn * 128;
#pragma unroll
  for (int mi = 0; mi < 4; ++mi)
#pragma unroll
    for (int ni = 0; ni < 4; ++ni)
#pragma unroll
      for (int r = 0; r < 4; ++r) {
        int row = wm + mi * 16 + lk * 4 + r;
        int col = wn + ni * 16 + lr;
        float up = au[mi][ni][r];
        float gv = ag[mi][ni][r];
        He[(size_t)row * HDIM + col] = f2bf(up * gv / (1.f + __expf(-gv)));
      }
}

// ------------- GEMM2: out = hidden @ w_downT, 128x128 tile, full double-buffer -------------
__global__ __launch_bounds__(256, 2) void gemm2_down(
    const unsigned short* __restrict__ Hid,
    const unsigned short* __restrict__ WdT,
    float* __restrict__ Out) {
  __shared__ unsigned short sA[2][128 * 64];   // 32 KiB
  __shared__ unsigned short sB[2][128 * 64];   // 32 KiB
  const int bn = blockIdx.x;   // d tile 0..15
  const int bm = blockIdx.y;   // token tile 0..31
  const int e  = blockIdx.z;
  const unsigned short* Ae = Hid + ((size_t)e * TTOK + bm * 128) * HDIM;
  const unsigned short* Be = WdT + ((size_t)e * DDIM + (size_t)bn * 128) * HDIM;
  const int tid = threadIdx.x;
  const int lane = tid & 63;
  const int wid = tid >> 6;
  const int wm = (wid & 1) * 64;
  const int wn = (wid >> 1) * 64;
  const int lr = lane & 15;
  const int lk = lane >> 4;

  f32x4 acc[4][4];
#pragma unroll
  for (int i = 0; i < 4; ++i)
#pragma unroll
    for (int j = 0; j < 4; ++j) acc[i][j] = f32x4{0.f, 0.f, 0.f, 0.f};

  const int NT = HDIM / 64;   // 64
  // Prologue: AB(0) (8 loads), AB(1) (8 loads).
  stage128x64(Ae, HDIM, sA[0], tid);
  stage128x64(Be, HDIM, sB[0], tid);
  stage128x64(Ae + 64, HDIM, sA[1], tid);
  stage128x64(Be + 64, HDIM, sB[1], tid);

  for (int t = 0; t < NT; ++t) {
    const int cur = t & 1;
    if (t + 1 < NT) { WAIT_VM(8); } else { WAIT_VM(0); }
    SBAR();
    SCHED0();
    const unsigned short* a = sA[cur];
    const unsigned short* b = sB[cur];
#pragma unroll
    for (int kh = 0; kh < 2; ++kh) {
      const int cg = kh * 4 + lk;
      bf16x8 af[4], bf[4];
#pragma unroll
      for (int mi = 0; mi < 4; ++mi) af[mi] = read_frag(a, wm + mi * 16 + lr, cg);
#pragma unroll
      for (int ni = 0; ni < 4; ++ni) bf[ni] = read_frag(b, wn + ni * 16 + lr, cg);
#pragma unroll
      for (int mi = 0; mi < 4; ++mi)
#pragma unroll
        for (int ni = 0; ni < 4; ++ni)
          acc[mi][ni] = MFMA_BF16(af[mi], bf[ni], acc[mi][ni]);
    }
    SCHED0();
    WAIT_LGKM0();
    SBAR();
    SCHED0();
    if (t + 2 < NT) {
      stage128x64(Ae + (t + 2) * 64, HDIM, sA[cur], tid);   // AB(t+2): 8 loads
      stage128x64(Be + (t + 2) * 64, HDIM, sB[cur], tid);
    }
  }

  float* Oe = Out + ((size_t)e * TTOK + bm * 128) * DDIM + (size_t)bn * 128;
#pragma unroll
  for (int mi = 0; mi < 4; ++mi)
#pragma unroll
    for (int ni = 0; ni < 4; ++ni)
#pragma unroll
      for (int r = 0; r < 4; ++r) {
        int row = wm + mi * 16 + lk * 4 + r;
        int col = wn + ni * 16 + lr;
        Oe[(size_t)row * DDIM + col] = acc[mi][ni][r];
      }
}

extern "C" void kernel_launch(void* const* d_in, const int* in_sizes, int n_in,
                              void* d_out, int out_size, void* d_ws, size_t ws_size,
                              hipStream_t stream) {
  const float* x = (const float*)d_in[0];
  const float* wug = (const float*)d_in[1];
  const float* wd = (const float*)d_in[2];
  float* out = (float*)d_out;

  unsigned short* xb   = (unsigned short*)d_ws;                    // 32768*2048
  unsigned short* wugb = xb   + (size_t)NTOK * DDIM;               // 8*8192*2048
  unsigned short* wdT  = wugb + (size_t)NEXP * 2 * HDIM * DDIM;    // 8*2048*4096
  unsigned short* hid  = wdT  + (size_t)NEXP * DDIM * HDIM;        // 8*4096*4096

  cvt_kernel<<<4096, 256, 0, stream>>>(x, xb, (long)NTOK * DDIM / 4);
  cvt_kernel<<<4096, 256, 0, stream>>>(wug, wugb, (long)NEXP * 2 * HDIM * DDIM / 4);
  transpose_wd<<<dim3(DDIM / 64, HDIM / 64, NEXP), 256, 0, stream>>>(wd, wdT);
  gemm1_swiglu<<<dim3(HDIM / 128, TTOK / 128, NEXP), 256, 0, stream>>>(xb, wugb, hid);
  gemm2_down<<<dim3(DDIM / 128, TTOK / 128, NEXP), 256, 0, stream>>>(hid, wdT, out);
}